// Round 10
// baseline (161.146 us; speedup 1.0000x reference)
//
#include <hip/hip_runtime.h>
#include <stdint.h>

#define N 8192
#define NCLS 80
#define CCAP 128            // per-class member cap (expected ~51; >10 sigma)
#define TAGA 0xA5B00000u    // low-word tag of a published cls
#define TAGB 0x5AC10000u    // high-word tag (differs -> uniform fill can't fake both)

// Within-class order key: ascending key == descending conf (conf>0.5 =>
// positive => bit-monotonic), tie -> lower index. Identical relative order
// to the reference's global stable argsort restricted to one class.
__device__ __forceinline__ unsigned long long makeKey(float c, int idx) {
    return ((unsigned long long)(~__float_as_uint(c)) << 32) | (unsigned int)idx;
}

// ---------------- single fused kernel, data-flow handshake --------------
// 512 blocks x 256 thr, all co-resident (2 blocks/CU by occupancy:
// ~30 VGPR, 6.2 KB LDS, __launch_bounds__(256,2)) -> the per-element
// producer->consumer spin below cannot deadlock.
//  * owner part (all blocks): 16-thread cooperative argmax for 16 owned
//    elements; writes cls channel + full zero rows for invalid; PUBLISHES
//    cls as a double-tagged u64 via device-scope release store.
//  * class part (blocks 0..79): membership from acquire-loaded tagged
//    words (coalesced 8 B/lane; round-8 lesson: transactions, not bytes).
//    Tag check defeats any byte/dword-uniform poison pattern; the
//    harness's per-iteration workspace poison is what resets the
//    handshake between iterations. Per-class exact NMS (validated
//    bit-exact rounds 6-9, absmax 0.0) then writes valid rows.
__global__ __launch_bounds__(256, 2) void k_all(
    const float* __restrict__ box,
    const float* __restrict__ conf,
    const float* __restrict__ logits,
    unsigned long long* __restrict__ pub,
    float* __restrict__ out)
{
#pragma clang fp contract(off)
    const int tid = threadIdx.x;
    const int bid = blockIdx.x;

    // ================= owner part: 16 elements, 16 threads each =========
    {
        const int i = bid * 16 + (tid >> 4);
        const int s = tid & 15;
        // thread s covers logits[4s..4s+3] (and [64+4s..67+4s] for s<4) in
        // ascending index order with strict > => first-max-wins; combine
        // prefers greater value, tie -> lower index => exact argmax.
        const float4* lp4 = (const float4*)(logits + (size_t)i * NCLS);
        float4 v = lp4[s];
        int bi = 4 * s;
        float best = v.x;
        if (v.y > best) { best = v.y; bi = 4 * s + 1; }
        if (v.z > best) { best = v.z; bi = 4 * s + 2; }
        if (v.w > best) { best = v.w; bi = 4 * s + 3; }
        if (s < 4) {
            float4 w = lp4[16 + s];
            int b1 = 64 + 4 * s;
            if (w.x > best) { best = w.x; bi = b1; }
            if (w.y > best) { best = w.y; bi = b1 + 1; }
            if (w.z > best) { best = w.z; bi = b1 + 2; }
            if (w.w > best) { best = w.w; bi = b1 + 3; }
        }
        for (int off = 8; off; off >>= 1) {
            float ob = __shfl_down(best, off, 16);
            int   oi = __shfl_down(bi, off, 16);
            if (ob > best || (ob == best && oi < bi)) { best = ob; bi = oi; }
        }
        if (s == 0) {
            out[5 * N + i] = (float)bi;
            if (!(conf[i] > 0.5f)) {         // invalid: full zero row here
                out[i * 5 + 0] = 0.0f;
                out[i * 5 + 1] = 0.0f;
                out[i * 5 + 2] = 0.0f;
                out[i * 5 + 3] = 0.0f;
                out[i * 5 + 4] = 0.0f;
                out[6 * N + i] = 0.0f;
            }
            unsigned long long pv =
                ((unsigned long long)(TAGB | (unsigned)bi) << 32)
                | (unsigned long long)(TAGA | (unsigned)bi);
            __hip_atomic_store(&pub[i], pv, __ATOMIC_RELEASE,
                               __HIP_MEMORY_SCOPE_AGENT);
        }
    }

    if (bid >= NCLS) return;

    // ================= class part: exact NMS for class c = bid ==========
    __shared__ int n;
    __shared__ unsigned short uidx[CCAP];           // unsorted member idx
    __shared__ unsigned long long ukey[CCAP];
    __shared__ unsigned short sidx[CCAP];           // sorted by class rank
    __shared__ float4 sbox[CCAP];                   // corners x1,y1,x2,y2
    __shared__ float  sar[CCAP];
    __shared__ unsigned long long supmat[CCAP][2];  // bit b: a suppresses b
    __shared__ unsigned long long keepm[2];

    const unsigned cls = (unsigned)bid;
    if (tid == 0) n = 0;
    supmat[tid >> 1][tid & 1] = 0ULL;               // 256 words, 1/thread
    __syncthreads();

    // membership: spin on the tagged publication of each valid element.
    // Coalesced (lane l reads pub[q*256+l], 8 B/lane). Spin cap: on
    // protocol failure we produce wrong-but-terminating results (caught
    // by the harness check) instead of a hang.
    for (int q = 0; q < N / 256; ++q) {
        const int i = q * 256 + tid;
        const float c = conf[i];
        if (c > 0.5f) {
            unsigned long long pv;
            int spin = 0;
            for (;;) {
                pv = __hip_atomic_load(&pub[i], __ATOMIC_ACQUIRE,
                                       __HIP_MEMORY_SCOPE_AGENT);
                unsigned lo = (unsigned)pv, hi = (unsigned)(pv >> 32);
                if ((lo & 0xFFFF0000u) == TAGA &&
                    (hi & 0xFFFF0000u) == TAGB &&
                    (lo & 0xFFFFu) == (hi & 0xFFFFu)) break;
                if (++spin > (1 << 22)) break;
                __builtin_amdgcn_s_sleep(2);
            }
            if (((unsigned)pv & 0xFFFFu) == cls) {
                int p = atomicAdd(&n, 1);
                if (p < CCAP) {
                    uidx[p] = (unsigned short)i;
                    ukey[p] = makeKey(c, i);
                }
            }
        }
    }
    __syncthreads();
    int nn = n; if (nn > CCAP) nn = CCAP;

    // exact in-class rank (stable key) + scatter + stage geometry
    if (tid < nn) {
        unsigned long long mk = ukey[tid];
        int r = 0;
        for (int k = 0; k < nn; ++k) r += (ukey[k] < mk) ? 1 : 0;
        int i = uidx[tid];
        float4 b = ((const float4*)box)[i];          // x, y, w, h
        float hw = b.z * 0.5f, hh = b.w * 0.5f;      // == w/2 exactly
        sidx[r] = (unsigned short)i;
        sbox[r] = make_float4(b.x - hw, b.y - hh, b.x + hw, b.y + hh);
        sar[r]  = b.z * b.w;
    }
    __syncthreads();

    // pairwise IoU -> suppression bits (a = earlier rank, b = later)
    const int total = nn * nn;
    for (int t = tid; t < total; t += 256) {
        int a = t / nn, b = t - a * nn;
        if (b > a) {
            float4 A = sbox[a], B = sbox[b];
            // exact float32 op order of the reference:
            float iw = fminf(A.z, B.z) - fmaxf(A.x, B.x);
            iw = fmaxf(iw, 0.0f);
            float ih = fminf(A.w, B.w) - fmaxf(A.y, B.y);
            ih = fmaxf(ih, 0.0f);
            float inter = iw * ih;
            float uni = sar[a] + sar[b] - inter;
            float iou = __fdiv_rn(inter, uni);       // IEEE-rounded divide
            if (iou > 0.5f)
                atomicOr(&supmat[a][b >> 6], 1ULL << (b & 63));
        }
    }
    __syncthreads();

    // sequential greedy scan (reference semantics, bit-exact): a kept row
    // clears its marked later rows; supmat[a] holds only bits b>a.
    if (tid == 0) {
        unsigned long long k0 = (nn >= 64) ? ~0ULL : ((1ULL << nn) - 1ULL);
        unsigned long long k1 = (nn >= 128) ? ~0ULL
                              : (nn > 64) ? ((1ULL << (nn - 64)) - 1ULL) : 0ULL;
        for (int a = 0; a < nn; ++a) {
            bool ka = (a < 64) ? ((k0 >> a) & 1ULL) : ((k1 >> (a - 64)) & 1ULL);
            if (ka) { k0 &= ~supmat[a][0]; k1 &= ~supmat[a][1]; }
        }
        keepm[0] = k0; keepm[1] = k1;
    }
    __syncthreads();

    // output rows for this class's members (box/conf re-reads are L2-hot)
    if (tid < nn) {
        int i = sidx[tid];
        float m = (float)((keepm[tid >> 6] >> (tid & 63)) & 1ULL);
        float4 b = ((const float4*)box)[i];
        out[i * 5 + 0] = b.x * m;
        out[i * 5 + 1] = b.y * m;
        out[i * 5 + 2] = b.z * m;
        out[i * 5 + 3] = b.w * m;
        out[i * 5 + 4] = conf[i] * m;
        out[6 * N + i] = m;
    }
}

// ---------------- launch -------------------------------------------------
extern "C" void kernel_launch(void* const* d_in, const int* in_sizes, int n_in,
                              void* d_out, int out_size, void* d_ws, size_t ws_size,
                              hipStream_t stream) {
    const float* box    = (const float*)d_in[0];
    const float* conf   = (const float*)d_in[1];
    const float* logits = (const float*)d_in[2];
    float* out = (float*)d_out;

    // 64 KB tagged-publication array; re-poisoned (== reset) by the
    // harness before every iteration, which is what makes the tag
    // handshake sound across iterations.
    unsigned long long* pub = (unsigned long long*)d_ws;

    k_all<<<N / 16, 256, 0, stream>>>(box, conf, logits, pub, out);
}